// Round 9
// baseline (256.668 us; speedup 1.0000x reference)
//
#include <hip/hip_runtime.h>
#include <hip/hip_fp16.h>

#define NEG 0.2f
#define BUCKET_SHIFT 7
#define CAP 3200
#define PCHUNK 4096

typedef _Float16 h8 __attribute__((ext_vector_type(8)));
typedef float f4v __attribute__((ext_vector_type(4)));

// ============ device bodies for the fused stage kernels ============

// Weight convert: fp32 W[k][n] (128x128) -> fp16 fragment-order.
__device__ __forceinline__ void wconv_dev(int bid, const float* __restrict__ W2,
                                          const float* __restrict__ rW2,
                                          float4* __restrict__ W2f,
                                          float4* __restrict__ rW2f) {
    int c = bid * 256 + threadIdx.x;  // 0..4095
    int which = c >> 11;
    int cc = c & 2047;
    int kb = cc >> 9, rem = cc & 511, t = rem >> 6, lane = rem & 63;
    int n = (t << 4) + (lane & 15);
    int k0 = (kb << 5) + ((lane >> 4) << 3);
    const float* S = which ? rW2 : W2;
    h8 v;
#pragma unroll
    for (int i = 0; i < 8; i++) v[i] = (_Float16)S[(k0 + i) * 128 + n];
    ((h8*)(which ? rW2f : W2f))[cc] = v;
}

// Partition edges into per-bucket slabs. smem >= 20480 B.
__device__ __forceinline__ void partition_dev(char* smem, int bid,
                                              const int* __restrict__ src,
                                              const int* __restrict__ dst,
                                              int* __restrict__ cursor,
                                              unsigned* __restrict__ part,
                                              int E, int NB) {
    unsigned* stash = (unsigned*)smem;      // PCHUNK
    int* hist = (int*)(smem + PCHUNK * 4);  // 512
    int* base = hist + 512;                 // 512
    const int tid = threadIdx.x;
    const int e0 = bid * PCHUNK;

    for (int i = tid; i < NB; i += 256) hist[i] = 0;
    __syncthreads();

    for (int i = tid; i < PCHUNK; i += 256) {
        int e = e0 + i;
        unsigned pk = 0xFFFFFFFFu;
        if (e < E) {
            int d = dst[e];
            pk = ((unsigned)d << 16) | (unsigned)src[e];
            atomicAdd(&hist[d >> BUCKET_SHIFT], 1);
        }
        stash[i] = pk;
    }
    __syncthreads();

    for (int i = tid; i < NB; i += 256) {
        int hcnt = hist[i];
        base[i] = hcnt ? atomicAdd(&cursor[i], hcnt) : 0;
        hist[i] = 0;  // reuse as intra-block cursor
    }
    __syncthreads();

    for (int i = tid; i < PCHUNK; i += 256) {
        unsigned pk = stash[i];
        if (pk != 0xFFFFFFFFu) {
            int b = pk >> (16 + BUCKET_SHIFT);
            int r = base[b] + atomicAdd(&hist[b], 1);
            if (r < CAP) part[(size_t)b * CAP + r] = pk;
        }
    }
}

// One block per bucket: node count/scan/scatter in LDS. smem >= 14848 B.
__device__ __forceinline__ void bucket_dev(char* smem, int b,
                                           const int* __restrict__ cursor,
                                           const unsigned* __restrict__ part,
                                           int* __restrict__ csr_src,
                                           int* __restrict__ row_beg,
                                           int* __restrict__ row_end, int N) {
    int* cnt = (int*)smem;  // 128
    int* sc = cnt + 128;    // 128
    int* ex = sc + 128;     // 128
    int* cur = ex + 128;    // 128
    int* lcsr = cur + 128;  // CAP
    const int tid = threadIdx.x;
    int m = cursor[b];
    m = m < CAP ? m : CAP;
    if (tid < 128) cnt[tid] = 0;
    __syncthreads();

    const unsigned* pp = part + (size_t)b * CAP;
    for (int i = tid; i < m; i += 256) atomicAdd(&cnt[(pp[i] >> 16) & 127], 1);
    __syncthreads();

    if (tid < 128) sc[tid] = cnt[tid];
    __syncthreads();
    for (int off = 1; off < 128; off <<= 1) {
        int t = (tid < 128 && tid >= off) ? sc[tid - off] : 0;
        __syncthreads();
        if (tid < 128) sc[tid] += t;
        __syncthreads();
    }
    if (tid < 128) {
        ex[tid] = sc[tid] - cnt[tid];
        cur[tid] = 0;
    }
    __syncthreads();

    for (int i = tid; i < m; i += 256) {
        unsigned pk = pp[i];
        int dlo = (pk >> 16) & 127;
        int r = atomicAdd(&cur[dlo], 1);
        lcsr[ex[dlo] + r] = (int)(pk & 0xFFFFu);
    }
    __syncthreads();

    const int gbase = b * CAP;
    for (int i = tid; i < m; i += 256) csr_src[gbase + i] = lcsr[i];
    int n = (b << BUCKET_SHIFT) + tid;
    if (tid < 128 && n < N) {
        row_beg[n] = gbase + ex[tid];
        row_end[n] = gbase + sc[tid];
    }
}

// Layer-1 GEMM (K=64, fp32 VALU) + el/er epilogue, fp16 feat out. smem >= 16384 B.
__device__ __forceinline__ void gemm_el_dev(char* smem, int bid,
                                            const float* __restrict__ A,
                                            const float* __restrict__ W,
                                            const float* __restrict__ al,
                                            const float* __restrict__ ar,
                                            __half* __restrict__ feat_h,
                                            float* __restrict__ el,
                                            float* __restrict__ er, int N) {
    constexpr int K = 64;
    float* As = (float*)smem;  // 64*K
    const int c = threadIdx.x & 31;
    const int rg = threadIdx.x >> 5;
    const int row0 = bid << 6;
    const int K4 = K >> 2;

    const float4* Av = (const float4*)A;
    float4* AsV = (float4*)As;
    for (int idx = threadIdx.x; idx < 16 * K; idx += 256) {
        int rr = idx / K4, kk4 = idx - rr * K4;
        int row = row0 + rr;
        float4 v = make_float4(0.f, 0.f, 0.f, 0.f);
        if (row < N) v = Av[(size_t)row * K4 + kk4];
        AsV[rr * K4 + kk4] = v;
    }
    __syncthreads();

    const float4* Wv = (const float4*)W;
    float4 acc[8];
#pragma unroll
    for (int i = 0; i < 8; i++) acc[i] = make_float4(0.f, 0.f, 0.f, 0.f);

    for (int k4 = 0; k4 < K4; k4++) {
        float4 a[8];
#pragma unroll
        for (int i = 0; i < 8; i++) a[i] = AsV[(rg * 8 + i) * K4 + k4];
#pragma unroll
        for (int kk = 0; kk < 4; kk++) {
            float4 w = Wv[((k4 << 2) + kk) * 32 + c];
#pragma unroll
            for (int i = 0; i < 8; i++) {
                float av = kk == 0 ? a[i].x : kk == 1 ? a[i].y : kk == 2 ? a[i].z : a[i].w;
                acc[i].x += av * w.x;
                acc[i].y += av * w.y;
                acc[i].z += av * w.z;
                acc[i].w += av * w.w;
            }
        }
    }

    __half2* Fh2 = (__half2*)feat_h;
#pragma unroll
    for (int i = 0; i < 8; i++) {
        int row = row0 + rg * 8 + i;
        if (row < N) {
            size_t o = ((size_t)row << 6) + (c << 1);
            Fh2[o] = __floats2half2_rn(acc[i].x, acc[i].y);
            Fh2[o + 1] = __floats2half2_rn(acc[i].z, acc[i].w);
        }
    }

    float4 alv = ((const float4*)al)[c];
    float4 arv = ((const float4*)ar)[c];
    float pel[8], per_[8];
#pragma unroll
    for (int i = 0; i < 8; i++) {
        pel[i] = acc[i].x * alv.x + acc[i].y * alv.y + acc[i].z * alv.z + acc[i].w * alv.w;
        per_[i] = acc[i].x * arv.x + acc[i].y * arv.y + acc[i].z * arv.z + acc[i].w * arv.w;
    }
#pragma unroll
    for (int m = 1; m < 8; m <<= 1) {
#pragma unroll
        for (int i = 0; i < 8; i++) {
            pel[i] += __shfl_xor(pel[i], m);
            per_[i] += __shfl_xor(per_[i], m);
        }
    }
    if ((c & 7) == 0) {
        int h = c >> 3;
#pragma unroll
        for (int i = 0; i < 8; i++) {
            int row = row0 + rg * 8 + i;
            if (row < N) {
                el[(row << 2) + h] = pel[i];
                er[(row << 2) + h] = per_[i];
            }
        }
    }
}

// ============ fused stage kernels ============
__global__ __launch_bounds__(256) void stage1_k(const float* __restrict__ W2,
                                                const float* __restrict__ rW2,
                                                float4* __restrict__ W2f,
                                                float4* __restrict__ rW2f,
                                                const int* __restrict__ src,
                                                const int* __restrict__ dst,
                                                int* __restrict__ cursor,
                                                unsigned* __restrict__ part,
                                                int E, int NB) {
    __shared__ __align__(16) char smem[20480];
    if (blockIdx.x < 16)
        wconv_dev(blockIdx.x, W2, rW2, W2f, rW2f);
    else
        partition_dev(smem, blockIdx.x - 16, src, dst, cursor, part, E, NB);
}

__global__ __launch_bounds__(256) void stage2_k(const int* __restrict__ cursor,
                                                const unsigned* __restrict__ part,
                                                int* __restrict__ csr_src,
                                                int* __restrict__ row_beg,
                                                int* __restrict__ row_end, int NB,
                                                const float* __restrict__ x,
                                                const float* __restrict__ W1,
                                                const float* __restrict__ al1,
                                                const float* __restrict__ ar1,
                                                __half* __restrict__ featA,
                                                float* __restrict__ el,
                                                float* __restrict__ er, int N) {
    __shared__ __align__(16) char smem[16384];
    if ((int)blockIdx.x < NB)
        bucket_dev(smem, blockIdx.x, cursor, part, csr_src, row_beg, row_end, N);
    else
        gemm_el_dev(smem, blockIdx.x - NB, x, W1, al1, ar1, featA, el, er, N);
}

// ------- MFMA GEMM core (K=128, 64 rows/block, 4 waves) -------
#define MFMA_STAGE_AND_LOOP()                                                   \
    const int tid = threadIdx.x;                                                \
    const int row0 = blockIdx.x << 6;                                           \
    for (int i = tid; i < 2048; i += 256) WsF[i] = Wf[i];                       \
    const float4* Afv = (const float4*)A;                                       \
    for (int idx = tid; idx < 1024; idx += 256) {                               \
        int r = idx >> 4, kc = idx & 15;                                        \
        float4 v = make_float4(0.f, 0.f, 0.f, 0.f);                             \
        int row = row0 + r;                                                     \
        if (row < N) v = Afv[(size_t)row * 16 + kc];                            \
        int d = ((r >> 4) * 4 + (kc >> 2)) * 64 + (kc & 3) * 16 + (r & 15);     \
        AsF[d] = v;                                                             \
    }                                                                           \
    __syncthreads();                                                            \
    const int w = tid >> 6;                                                     \
    const int lane = tid & 63;                                                  \
    const h8* Ah = (const h8*)AsF;                                              \
    const h8* Wh = (const h8*)WsF;                                              \
    f4v acc[8];                                                                 \
    _Pragma("unroll") for (int t = 0; t < 8; t++) acc[t] = (f4v){0.f, 0.f, 0.f, 0.f}; \
    _Pragma("unroll") for (int kb = 0; kb < 4; kb++) {                          \
        h8 af = Ah[(w * 4 + kb) * 64 + lane];                                   \
        _Pragma("unroll") for (int t = 0; t < 8; t++) {                         \
            h8 bf = Wh[(kb * 8 + t) * 64 + lane];                               \
            acc[t] = __builtin_amdgcn_mfma_f32_16x16x32_f16(af, bf, acc[t], 0, 0, 0); \
        }                                                                       \
    }                                                                           \
    const int c16 = lane & 15;                                                  \
    const int rg = lane >> 4;

// Layer-2 MFMA GEMM: feat = h2@W2 (fp16 out) + el/er epilogue.
__global__ __launch_bounds__(256) void mfma_el_k(const _Float16* __restrict__ A,
                                                 const float4* __restrict__ Wf,
                                                 const float* __restrict__ al,
                                                 const float* __restrict__ ar,
                                                 _Float16* __restrict__ feat,
                                                 float* __restrict__ el,
                                                 float* __restrict__ er, int N) {
    __shared__ float4 WsF[2048];
    __shared__ float4 AsF[1024];
    MFMA_STAGE_AND_LOOP()

    float alv[8], arv[8];
#pragma unroll
    for (int t = 0; t < 8; t++) {
        alv[t] = al[(t << 4) + c16];
        arv[t] = ar[(t << 4) + c16];
    }
    float pel[4][4], per_[4][4];
#pragma unroll
    for (int j = 0; j < 4; j++)
#pragma unroll
        for (int hh = 0; hh < 4; hh++) {
            pel[j][hh] = acc[2 * hh][j] * alv[2 * hh] + acc[2 * hh + 1][j] * alv[2 * hh + 1];
            per_[j][hh] = acc[2 * hh][j] * arv[2 * hh] + acc[2 * hh + 1][j] * arv[2 * hh + 1];
        }
#pragma unroll
    for (int m = 1; m < 16; m <<= 1)
#pragma unroll
        for (int j = 0; j < 4; j++)
#pragma unroll
            for (int hh = 0; hh < 4; hh++) {
                pel[j][hh] += __shfl_xor(pel[j][hh], m);
                per_[j][hh] += __shfl_xor(per_[j][hh], m);
            }
    if (c16 == 0) {
#pragma unroll
        for (int j = 0; j < 4; j++) {
            int row = row0 + (w << 4) + (rg << 2) + j;
            if (row < N) {
                ((float4*)el)[row] = make_float4(pel[j][0], pel[j][1], pel[j][2], pel[j][3]);
                ((float4*)er)[row] = make_float4(per_[j][0], per_[j][1], per_[j][2], per_[j][3]);
            }
        }
    }

    _Float16* As2 = (_Float16*)AsF + (w << 11);
#pragma unroll
    for (int t = 0; t < 8; t++)
#pragma unroll
        for (int j = 0; j < 4; j++)
            As2[((rg << 2) + j) * 128 + (t << 4) + c16] = (_Float16)acc[t][j];
    __asm__ volatile("s_waitcnt lgkmcnt(0)" ::: "memory");
    const float4* As2v = (const float4*)As2;
    float4* featv = (float4*)feat;
#pragma unroll
    for (int ii = 0; ii < 4; ii++) {
        int ch = ii * 64 + lane;
        int row = row0 + (w << 4) + (ch >> 4);
        if (row < N) featv[(size_t)row * 16 + (ch & 15)] = As2v[ch];
    }
}

// Layer-2 residual + Layer-3 projections, fused; h3 never stored.
// feat3 written with stride 8 (padded) for aligned float4 gathers in pull6f.
__global__ __launch_bounds__(256) void mfma_res_k(const _Float16* __restrict__ A,
                                                  const float4* __restrict__ Wf,
                                                  const _Float16* __restrict__ rsth,
                                                  const float* __restrict__ b2,
                                                  const float* __restrict__ W3,
                                                  const float* __restrict__ resW3,
                                                  const float* __restrict__ b3,
                                                  float* __restrict__ feat3,
                                                  float* __restrict__ res3, int N) {
    __shared__ float4 WsF[2048];
    __shared__ float4 AsF[1024];
    MFMA_STAGE_AND_LOOP()

    float4* As2v = (float4*)AsF + (w << 8);
#pragma unroll
    for (int ii = 0; ii < 4; ii++) {
        int ch = ii * 64 + lane;
        int row = row0 + (w << 4) + (ch >> 4);
        float4 v = make_float4(0.f, 0.f, 0.f, 0.f);
        if (row < N) v = ((const float4*)rsth)[(size_t)row * 16 + (ch & 15)];
        As2v[ch] = v;
    }
    __asm__ volatile("s_waitcnt lgkmcnt(0)" ::: "memory");
    const _Float16* As2 = (const _Float16*)As2v;

    float b2v[8];
#pragma unroll
    for (int t = 0; t < 8; t++) b2v[t] = b2[(t << 4) + c16];

    float hv[8][4];
#pragma unroll
    for (int t = 0; t < 8; t++)
#pragma unroll
        for (int j = 0; j < 4; j++) {
            float rv = (float)As2[((rg << 2) + j) * 128 + (t << 4) + c16];
            hv[t][j] = fmaxf(acc[t][j] + rv + b2v[t], 0.f);
        }

    float f3[4][6], r3[4][6];
#pragma unroll
    for (int j = 0; j < 4; j++)
#pragma unroll
        for (int h = 0; h < 6; h++) {
            f3[j][h] = 0.f;
            r3[j][h] = 0.f;
        }
#pragma unroll
    for (int t = 0; t < 8; t++) {
        int col = (t << 4) + c16;
        const float* w3p = W3 + col * 6;
        const float* rwp = resW3 + col * 6;
#pragma unroll
        for (int h = 0; h < 6; h++) {
            float w3 = w3p[h], rw = rwp[h];
#pragma unroll
            for (int j = 0; j < 4; j++) {
                f3[j][h] = fmaf(hv[t][j], w3, f3[j][h]);
                r3[j][h] = fmaf(hv[t][j], rw, r3[j][h]);
            }
        }
    }
#pragma unroll
    for (int m = 1; m < 16; m <<= 1)
#pragma unroll
        for (int j = 0; j < 4; j++)
#pragma unroll
            for (int h = 0; h < 6; h++) {
                f3[j][h] += __shfl_xor(f3[j][h], m);
                r3[j][h] += __shfl_xor(r3[j][h], m);
            }
    if (c16 == 0) {
#pragma unroll
        for (int j = 0; j < 4; j++) {
            int row = row0 + (w << 4) + (rg << 2) + j;
            if (row < N) {
#pragma unroll
                for (int h = 0; h < 6; h++) {
                    feat3[(size_t)row * 8 + h] = f3[j][h];
                    res3[row * 6 + h] = r3[j][h] + b3[h];
                }
            }
        }
    }
}

// ---- Pull aggregation (H=4, D=32, fp16): 2 nodes/wave, 8 B/lane ----
// Half-wave (32 lanes) per node; lane q -> cols 4q..4q+3, head q>>3.
template <bool BR>
__global__ __launch_bounds__(256) void pull2_k(const int* __restrict__ row_beg,
                                               const int* __restrict__ row_end,
                                               const int* __restrict__ csr_src,
                                               const float* __restrict__ el,
                                               const float* __restrict__ er,
                                               const __half* __restrict__ feat_h,
                                               const float* __restrict__ bias,
                                               __half* __restrict__ outp, int N) {
    int n = (blockIdx.x << 3) + (threadIdx.x >> 5);
    if (n >= N) return;
    unsigned q = threadIdx.x & 31;
    unsigned h = q >> 3;
    float erd = er[((unsigned)n << 2) + h];
    const uint2* feat4 = (const uint2*)feat_h;  // 8 B chunks, row stride 32
    int beg = row_beg[n], end = row_end[n];
    float a0 = 0.f, a1 = 0.f, a2 = 0.f, a3 = 0.f, den = 0.f;
    int p = beg;
    for (; p + 4 <= end; p += 4) {
        int s0 = csr_src[p], s1 = csr_src[p + 1];
        int s2 = csr_src[p + 2], s3 = csr_src[p + 3];
        float e0 = el[((unsigned)s0 << 2) + h];
        float e1 = el[((unsigned)s1 << 2) + h];
        float e2 = el[((unsigned)s2 << 2) + h];
        float e3 = el[((unsigned)s3 << 2) + h];
        uint2 g0 = feat4[((unsigned)s0 << 5) + q];
        uint2 g1 = feat4[((unsigned)s1 << 5) + q];
        uint2 g2 = feat4[((unsigned)s2 << 5) + q];
        uint2 g3 = feat4[((unsigned)s3 << 5) + q];
        float x0 = e0 + erd, x1 = e1 + erd, x2 = e2 + erd, x3 = e3 + erd;
        x0 = fmaxf(x0, NEG * x0);
        x1 = fmaxf(x1, NEG * x1);
        x2 = fmaxf(x2, NEG * x2);
        x3 = fmaxf(x3, NEG * x3);
        float w0 = __expf(x0), w1 = __expf(x1), w2 = __expf(x2), w3 = __expf(x3);
        den += (w0 + w1) + (w2 + w3);
        float2 lo, hi;
        lo = __half22float2(*(__half2*)&g0.x);
        hi = __half22float2(*(__half2*)&g0.y);
        a0 = fmaf(w0, lo.x, a0);
        a1 = fmaf(w0, lo.y, a1);
        a2 = fmaf(w0, hi.x, a2);
        a3 = fmaf(w0, hi.y, a3);
        lo = __half22float2(*(__half2*)&g1.x);
        hi = __half22float2(*(__half2*)&g1.y);
        a0 = fmaf(w1, lo.x, a0);
        a1 = fmaf(w1, lo.y, a1);
        a2 = fmaf(w1, hi.x, a2);
        a3 = fmaf(w1, hi.y, a3);
        lo = __half22float2(*(__half2*)&g2.x);
        hi = __half22float2(*(__half2*)&g2.y);
        a0 = fmaf(w2, lo.x, a0);
        a1 = fmaf(w2, lo.y, a1);
        a2 = fmaf(w2, hi.x, a2);
        a3 = fmaf(w2, hi.y, a3);
        lo = __half22float2(*(__half2*)&g3.x);
        hi = __half22float2(*(__half2*)&g3.y);
        a0 = fmaf(w3, lo.x, a0);
        a1 = fmaf(w3, lo.y, a1);
        a2 = fmaf(w3, hi.x, a2);
        a3 = fmaf(w3, hi.y, a3);
    }
    for (; p < end; p++) {
        int s0 = csr_src[p];
        float e0 = el[((unsigned)s0 << 2) + h];
        uint2 g0 = feat4[((unsigned)s0 << 5) + q];
        float x0 = e0 + erd;
        x0 = fmaxf(x0, NEG * x0);
        float w0 = __expf(x0);
        den += w0;
        float2 lo = __half22float2(*(__half2*)&g0.x);
        float2 hi = __half22float2(*(__half2*)&g0.y);
        a0 = fmaf(w0, lo.x, a0);
        a1 = fmaf(w0, lo.y, a1);
        a2 = fmaf(w0, hi.x, a2);
        a3 = fmaf(w0, hi.y, a3);
    }
    float inv = 1.f / den;  // den >= 1 edge (self-loops)
    float v0 = a0 * inv, v1 = a1 * inv, v2 = a2 * inv, v3 = a3 * inv;
    if (BR) {
        float4 bv = ((const float4*)bias)[q];
        v0 = fmaxf(v0 + bv.x, 0.f);
        v1 = fmaxf(v1 + bv.y, 0.f);
        v2 = fmaxf(v2 + bv.z, 0.f);
        v3 = fmaxf(v3 + bv.w, 0.f);
    }
    __half2 o01 = __floats2half2_rn(v0, v1);
    __half2 o23 = __floats2half2_rn(v2, v3);
    uint2 st;
    st.x = *(unsigned*)&o01;
    st.y = *(unsigned*)&o23;
    ((uint2*)outp)[((size_t)n << 5) + q] = st;
}

// Layer 3 pull + residual + head-mean, one thread per node (D=1, H=6).
// feat3 stride 8 -> two aligned float4 loads per edge.
__global__ __launch_bounds__(256) void pull6f_k(const int* __restrict__ row_beg,
                                                const int* __restrict__ row_end,
                                                const int* __restrict__ csr_src,
                                                const float* __restrict__ feat3,
                                                const float* __restrict__ al3,
                                                const float* __restrict__ ar3,
                                                const float* __restrict__ res3,
                                                float* __restrict__ out, int N) {
    int n = blockIdx.x * blockDim.x + threadIdx.x;
    if (n >= N) return;
    const float4* f4p = (const float4*)feat3;  // stride 2 per node
    float a3[6], fdr[6], acc[6], den[6];
#pragma unroll
    for (int h = 0; h < 6; h++) {
        a3[h] = al3[h];
        fdr[h] = feat3[(size_t)n * 8 + h] * ar3[h];
        acc[h] = 0.f;
        den[h] = 0.f;
    }
    int beg = row_beg[n], end = row_end[n];
    for (int p = beg; p < end; p++) {
        int s = csr_src[p];
        float4 fa = f4p[(size_t)s * 2];
        float4 fb = f4p[(size_t)s * 2 + 1];
        float f[6] = {fa.x, fa.y, fa.z, fa.w, fb.x, fb.y};
#pragma unroll
        for (int h = 0; h < 6; h++) {
            float x = fmaf(f[h], a3[h], fdr[h]);
            x = fmaxf(x, NEG * x);
            float w = __expf(x);
            den[h] += w;
            acc[h] = fmaf(w, f[h], acc[h]);
        }
    }
    float m = 0.f;
#pragma unroll
    for (int h = 0; h < 6; h++) m += acc[h] / den[h] + res3[n * 6 + h];
    out[n] = m * (1.f / 6.f);
}

extern "C" void kernel_launch(void* const* d_in, const int* in_sizes, int n_in,
                              void* d_out, int out_size, void* d_ws, size_t ws_size,
                              hipStream_t stream) {
    const float* x = (const float*)d_in[0];
    const int* src = (const int*)d_in[1];
    const int* dst = (const int*)d_in[2];
    const float* W1 = (const float*)d_in[3];
    const float* al1 = (const float*)d_in[4];
    const float* ar1 = (const float*)d_in[5];
    const float* b1 = (const float*)d_in[6];
    const float* W2 = (const float*)d_in[7];
    const float* al2 = (const float*)d_in[8];
    const float* ar2 = (const float*)d_in[9];
    const float* b2 = (const float*)d_in[10];
    const float* resW2 = (const float*)d_in[11];
    const float* W3 = (const float*)d_in[12];
    const float* al3 = (const float*)d_in[13];
    const float* ar3 = (const float*)d_in[14];
    const float* b3 = (const float*)d_in[15];
    const float* resW3 = (const float*)d_in[16];
    float* out = (float*)d_out;

    const int N = in_sizes[0] / 64;
    const int E = in_sizes[1];
    const int NB = (N + 127) >> BUCKET_SHIFT;

    // ---- workspace layout (float units) ----
    float* ws = (float*)d_ws;
    __half* featA = (__half*)ws;                     // N*128 fp16
    __half* h2h = (__half*)(ws + (size_t)N * 64);    // N*128 fp16 (layer-1 out)
    __half* rsth = (__half*)(ws + (size_t)N * 128);  // N*128 fp16 (layer-2 agg out)
    float* el = ws + (size_t)N * 192;                // N*4
    float* er = el + (size_t)N * 4;                  // N*4
    float* feat3 = el;                               // N*8 (stride 8) aliases el+er
    float* res3 = ws + (size_t)N * 200;              // N*6
    float* W2f = res3 + (size_t)N * 6;               // 8192 (2048 float4)
    float* rW2f = W2f + 8192;                        // 8192
    int* ip = (int*)(rW2f + 8192);
    int* cursor = ip;                                // 512 (memset)
    int* row_beg = cursor + 512;                     // N
    int* row_end = row_beg + N;                      // N
    unsigned* part = (unsigned*)(row_end + N);       // NB*CAP
    int* csr_src = (int*)(part + (size_t)NB * CAP);  // NB*CAP

    const int gN = (N + 255) / 256;
    const int gN64 = (N + 63) / 64;
    const int gNw8 = (N + 7) / 8;  // 2 nodes/wave pull blocks
    const int gP = (E + PCHUNK - 1) / PCHUNK;

    hipMemsetAsync(cursor, 0, sizeof(int) * 512, stream);
    // Stage 1 (fused, independent): weight fragments + edge partition.
    stage1_k<<<16 + gP, 256, 0, stream>>>(W2, resW2, (float4*)W2f, (float4*)rW2f,
                                          src, dst, cursor, part, E, NB);
    // Stage 2 (fused, independent): bucket CSR + layer-1 GEMM.
    stage2_k<<<NB + gN64, 256, 0, stream>>>(cursor, part, csr_src, row_beg, row_end,
                                            NB, x, W1, al1, ar1, featA, el, er, N);

    // ---- Layer 1 pull ----
    pull2_k<true><<<gNw8, 256, 0, stream>>>(row_beg, row_end, csr_src, el, er,
                                            featA, b1, h2h, N);

    // ---- Layer 2: MFMA GEMM + pull + fused residual/layer-3 projections ----
    mfma_el_k<<<gN64, 256, 0, stream>>>((const _Float16*)h2h, (const float4*)W2f,
                                        al2, ar2, (_Float16*)featA, el, er, N);
    pull2_k<false><<<gNw8, 256, 0, stream>>>(row_beg, row_end, csr_src, el, er,
                                             featA, nullptr, rsth, N);
    mfma_res_k<<<gN64, 256, 0, stream>>>((const _Float16*)h2h, (const float4*)rW2f,
                                         (const _Float16*)rsth, b2, W3, resW3, b3,
                                         feat3, res3, N);

    // ---- Layer 3: pull + residual + mean (fused) ----
    pull6f_k<<<gN, 256, 0, stream>>>(row_beg, row_end, csr_src, feat3, al3, ar3,
                                     res3, out, N);
}

// Round 10
// 253.073 us; speedup vs baseline: 1.0142x; 1.0142x over previous
//
#include <hip/hip_runtime.h>
#include <hip/hip_fp16.h>

#define NEG 0.2f
#define BUCKET_SHIFT 7
#define CAP 3200
#define PCHUNK 4096

typedef _Float16 h8 __attribute__((ext_vector_type(8)));
typedef float f4v __attribute__((ext_vector_type(4)));

// ============ device bodies for the fused stage kernels ============

// Weight convert: fp32 W[k][n] (128x128) -> fp16 fragment-order.
__device__ __forceinline__ void wconv_dev(int bid, const float* __restrict__ W2,
                                          const float* __restrict__ rW2,
                                          float4* __restrict__ W2f,
                                          float4* __restrict__ rW2f) {
    int c = bid * 256 + threadIdx.x;  // 0..4095
    int which = c >> 11;
    int cc = c & 2047;
    int kb = cc >> 9, rem = cc & 511, t = rem >> 6, lane = rem & 63;
    int n = (t << 4) + (lane & 15);
    int k0 = (kb << 5) + ((lane >> 4) << 3);
    const float* S = which ? rW2 : W2;
    h8 v;
#pragma unroll
    for (int i = 0; i < 8; i++) v[i] = (_Float16)S[(k0 + i) * 128 + n];
    ((h8*)(which ? rW2f : W2f))[cc] = v;
}

// Partition edges into per-bucket slabs. smem >= 20480 B.
__device__ __forceinline__ void partition_dev(char* smem, int bid,
                                              const int* __restrict__ src,
                                              const int* __restrict__ dst,
                                              int* __restrict__ cursor,
                                              unsigned* __restrict__ part,
                                              int E, int NB) {
    unsigned* stash = (unsigned*)smem;      // PCHUNK
    int* hist = (int*)(smem + PCHUNK * 4);  // 512
    int* base = hist + 512;                 // 512
    const int tid = threadIdx.x;
    const int e0 = bid * PCHUNK;

    for (int i = tid; i < NB; i += 256) hist[i] = 0;
    __syncthreads();

    for (int i = tid; i < PCHUNK; i += 256) {
        int e = e0 + i;
        unsigned pk = 0xFFFFFFFFu;
        if (e < E) {
            int d = dst[e];
            pk = ((unsigned)d << 16) | (unsigned)src[e];
            atomicAdd(&hist[d >> BUCKET_SHIFT], 1);
        }
        stash[i] = pk;
    }
    __syncthreads();

    for (int i = tid; i < NB; i += 256) {
        int hcnt = hist[i];
        base[i] = hcnt ? atomicAdd(&cursor[i], hcnt) : 0;
        hist[i] = 0;  // reuse as intra-block cursor
    }
    __syncthreads();

    for (int i = tid; i < PCHUNK; i += 256) {
        unsigned pk = stash[i];
        if (pk != 0xFFFFFFFFu) {
            int b = pk >> (16 + BUCKET_SHIFT);
            int r = base[b] + atomicAdd(&hist[b], 1);
            if (r < CAP) part[(size_t)b * CAP + r] = pk;
        }
    }
}

// One block per bucket: node count/scan/scatter in LDS. smem >= 14848 B.
__device__ __forceinline__ void bucket_dev(char* smem, int b,
                                           const int* __restrict__ cursor,
                                           const unsigned* __restrict__ part,
                                           int* __restrict__ csr_src,
                                           int* __restrict__ row_beg,
                                           int* __restrict__ row_end, int N) {
    int* cnt = (int*)smem;  // 128
    int* sc = cnt + 128;    // 128
    int* ex = sc + 128;     // 128
    int* cur = ex + 128;    // 128
    int* lcsr = cur + 128;  // CAP
    const int tid = threadIdx.x;
    int m = cursor[b];
    m = m < CAP ? m : CAP;
    if (tid < 128) cnt[tid] = 0;
    __syncthreads();

    const unsigned* pp = part + (size_t)b * CAP;
    for (int i = tid; i < m; i += 256) atomicAdd(&cnt[(pp[i] >> 16) & 127], 1);
    __syncthreads();

    if (tid < 128) sc[tid] = cnt[tid];
    __syncthreads();
    for (int off = 1; off < 128; off <<= 1) {
        int t = (tid < 128 && tid >= off) ? sc[tid - off] : 0;
        __syncthreads();
        if (tid < 128) sc[tid] += t;
        __syncthreads();
    }
    if (tid < 128) {
        ex[tid] = sc[tid] - cnt[tid];
        cur[tid] = 0;
    }
    __syncthreads();

    for (int i = tid; i < m; i += 256) {
        unsigned pk = pp[i];
        int dlo = (pk >> 16) & 127;
        int r = atomicAdd(&cur[dlo], 1);
        lcsr[ex[dlo] + r] = (int)(pk & 0xFFFFu);
    }
    __syncthreads();

    const int gbase = b * CAP;
    for (int i = tid; i < m; i += 256) csr_src[gbase + i] = lcsr[i];
    int n = (b << BUCKET_SHIFT) + tid;
    if (tid < 128 && n < N) {
        row_beg[n] = gbase + ex[tid];
        row_end[n] = gbase + sc[tid];
    }
}

// Layer-1 GEMM (K=64, fp32 VALU) + el/er epilogue, fp16 feat out. smem >= 16384 B.
__device__ __forceinline__ void gemm_el_dev(char* smem, int bid,
                                            const float* __restrict__ A,
                                            const float* __restrict__ W,
                                            const float* __restrict__ al,
                                            const float* __restrict__ ar,
                                            __half* __restrict__ feat_h,
                                            float* __restrict__ el,
                                            float* __restrict__ er, int N) {
    constexpr int K = 64;
    float* As = (float*)smem;  // 64*K
    const int c = threadIdx.x & 31;
    const int rg = threadIdx.x >> 5;
    const int row0 = bid << 6;
    const int K4 = K >> 2;

    const float4* Av = (const float4*)A;
    float4* AsV = (float4*)As;
    for (int idx = threadIdx.x; idx < 16 * K; idx += 256) {
        int rr = idx / K4, kk4 = idx - rr * K4;
        int row = row0 + rr;
        float4 v = make_float4(0.f, 0.f, 0.f, 0.f);
        if (row < N) v = Av[(size_t)row * K4 + kk4];
        AsV[rr * K4 + kk4] = v;
    }
    __syncthreads();

    const float4* Wv = (const float4*)W;
    float4 acc[8];
#pragma unroll
    for (int i = 0; i < 8; i++) acc[i] = make_float4(0.f, 0.f, 0.f, 0.f);

    for (int k4 = 0; k4 < K4; k4++) {
        float4 a[8];
#pragma unroll
        for (int i = 0; i < 8; i++) a[i] = AsV[(rg * 8 + i) * K4 + k4];
#pragma unroll
        for (int kk = 0; kk < 4; kk++) {
            float4 w = Wv[((k4 << 2) + kk) * 32 + c];
#pragma unroll
            for (int i = 0; i < 8; i++) {
                float av = kk == 0 ? a[i].x : kk == 1 ? a[i].y : kk == 2 ? a[i].z : a[i].w;
                acc[i].x += av * w.x;
                acc[i].y += av * w.y;
                acc[i].z += av * w.z;
                acc[i].w += av * w.w;
            }
        }
    }

    __half2* Fh2 = (__half2*)feat_h;
#pragma unroll
    for (int i = 0; i < 8; i++) {
        int row = row0 + rg * 8 + i;
        if (row < N) {
            size_t o = ((size_t)row << 6) + (c << 1);
            Fh2[o] = __floats2half2_rn(acc[i].x, acc[i].y);
            Fh2[o + 1] = __floats2half2_rn(acc[i].z, acc[i].w);
        }
    }

    float4 alv = ((const float4*)al)[c];
    float4 arv = ((const float4*)ar)[c];
    float pel[8], per_[8];
#pragma unroll
    for (int i = 0; i < 8; i++) {
        pel[i] = acc[i].x * alv.x + acc[i].y * alv.y + acc[i].z * alv.z + acc[i].w * alv.w;
        per_[i] = acc[i].x * arv.x + acc[i].y * arv.y + acc[i].z * arv.z + acc[i].w * arv.w;
    }
#pragma unroll
    for (int m = 1; m < 8; m <<= 1) {
#pragma unroll
        for (int i = 0; i < 8; i++) {
            pel[i] += __shfl_xor(pel[i], m);
            per_[i] += __shfl_xor(per_[i], m);
        }
    }
    if ((c & 7) == 0) {
        int h = c >> 3;
#pragma unroll
        for (int i = 0; i < 8; i++) {
            int row = row0 + rg * 8 + i;
            if (row < N) {
                el[(row << 2) + h] = pel[i];
                er[(row << 2) + h] = per_[i];
            }
        }
    }
}

// ============ fused stage kernels ============
__global__ __launch_bounds__(256) void stage1_k(const float* __restrict__ W2,
                                                const float* __restrict__ rW2,
                                                float4* __restrict__ W2f,
                                                float4* __restrict__ rW2f,
                                                const int* __restrict__ src,
                                                const int* __restrict__ dst,
                                                int* __restrict__ cursor,
                                                unsigned* __restrict__ part,
                                                int E, int NB) {
    __shared__ __align__(16) char smem[20480];
    if (blockIdx.x < 16)
        wconv_dev(blockIdx.x, W2, rW2, W2f, rW2f);
    else
        partition_dev(smem, blockIdx.x - 16, src, dst, cursor, part, E, NB);
}

__global__ __launch_bounds__(256) void stage2_k(const int* __restrict__ cursor,
                                                const unsigned* __restrict__ part,
                                                int* __restrict__ csr_src,
                                                int* __restrict__ row_beg,
                                                int* __restrict__ row_end, int NB,
                                                const float* __restrict__ x,
                                                const float* __restrict__ W1,
                                                const float* __restrict__ al1,
                                                const float* __restrict__ ar1,
                                                __half* __restrict__ featA,
                                                float* __restrict__ el,
                                                float* __restrict__ er, int N) {
    __shared__ __align__(16) char smem[16384];
    if ((int)blockIdx.x < NB)
        bucket_dev(smem, blockIdx.x, cursor, part, csr_src, row_beg, row_end, N);
    else
        gemm_el_dev(smem, blockIdx.x - NB, x, W1, al1, ar1, featA, el, er, N);
}

// ------- MFMA GEMM core (K=128, 64 rows/block, 4 waves) -------
#define MFMA_STAGE_AND_LOOP()                                                   \
    const int tid = threadIdx.x;                                                \
    const int row0 = blockIdx.x << 6;                                           \
    for (int i = tid; i < 2048; i += 256) WsF[i] = Wf[i];                       \
    const float4* Afv = (const float4*)A;                                       \
    for (int idx = tid; idx < 1024; idx += 256) {                               \
        int r = idx >> 4, kc = idx & 15;                                        \
        float4 v = make_float4(0.f, 0.f, 0.f, 0.f);                             \
        int row = row0 + r;                                                     \
        if (row < N) v = Afv[(size_t)row * 16 + kc];                            \
        int d = ((r >> 4) * 4 + (kc >> 2)) * 64 + (kc & 3) * 16 + (r & 15);     \
        AsF[d] = v;                                                             \
    }                                                                           \
    __syncthreads();                                                            \
    const int w = tid >> 6;                                                     \
    const int lane = tid & 63;                                                  \
    const h8* Ah = (const h8*)AsF;                                              \
    const h8* Wh = (const h8*)WsF;                                              \
    f4v acc[8];                                                                 \
    _Pragma("unroll") for (int t = 0; t < 8; t++) acc[t] = (f4v){0.f, 0.f, 0.f, 0.f}; \
    _Pragma("unroll") for (int kb = 0; kb < 4; kb++) {                          \
        h8 af = Ah[(w * 4 + kb) * 64 + lane];                                   \
        _Pragma("unroll") for (int t = 0; t < 8; t++) {                         \
            h8 bf = Wh[(kb * 8 + t) * 64 + lane];                               \
            acc[t] = __builtin_amdgcn_mfma_f32_16x16x32_f16(af, bf, acc[t], 0, 0, 0); \
        }                                                                       \
    }                                                                           \
    const int c16 = lane & 15;                                                  \
    const int rg = lane >> 4;

// Layer-2 MFMA GEMM: feat = h2@W2 (fp16 out) + el/er epilogue.
__global__ __launch_bounds__(256) void mfma_el_k(const _Float16* __restrict__ A,
                                                 const float4* __restrict__ Wf,
                                                 const float* __restrict__ al,
                                                 const float* __restrict__ ar,
                                                 _Float16* __restrict__ feat,
                                                 float* __restrict__ el,
                                                 float* __restrict__ er, int N) {
    __shared__ float4 WsF[2048];
    __shared__ float4 AsF[1024];
    MFMA_STAGE_AND_LOOP()

    float alv[8], arv[8];
#pragma unroll
    for (int t = 0; t < 8; t++) {
        alv[t] = al[(t << 4) + c16];
        arv[t] = ar[(t << 4) + c16];
    }
    float pel[4][4], per_[4][4];
#pragma unroll
    for (int j = 0; j < 4; j++)
#pragma unroll
        for (int hh = 0; hh < 4; hh++) {
            pel[j][hh] = acc[2 * hh][j] * alv[2 * hh] + acc[2 * hh + 1][j] * alv[2 * hh + 1];
            per_[j][hh] = acc[2 * hh][j] * arv[2 * hh] + acc[2 * hh + 1][j] * arv[2 * hh + 1];
        }
#pragma unroll
    for (int m = 1; m < 16; m <<= 1)
#pragma unroll
        for (int j = 0; j < 4; j++)
#pragma unroll
            for (int hh = 0; hh < 4; hh++) {
                pel[j][hh] += __shfl_xor(pel[j][hh], m);
                per_[j][hh] += __shfl_xor(per_[j][hh], m);
            }
    if (c16 == 0) {
#pragma unroll
        for (int j = 0; j < 4; j++) {
            int row = row0 + (w << 4) + (rg << 2) + j;
            if (row < N) {
                ((float4*)el)[row] = make_float4(pel[j][0], pel[j][1], pel[j][2], pel[j][3]);
                ((float4*)er)[row] = make_float4(per_[j][0], per_[j][1], per_[j][2], per_[j][3]);
            }
        }
    }

    _Float16* As2 = (_Float16*)AsF + (w << 11);
#pragma unroll
    for (int t = 0; t < 8; t++)
#pragma unroll
        for (int j = 0; j < 4; j++)
            As2[((rg << 2) + j) * 128 + (t << 4) + c16] = (_Float16)acc[t][j];
    __asm__ volatile("s_waitcnt lgkmcnt(0)" ::: "memory");
    const float4* As2v = (const float4*)As2;
    float4* featv = (float4*)feat;
#pragma unroll
    for (int ii = 0; ii < 4; ii++) {
        int ch = ii * 64 + lane;
        int row = row0 + (w << 4) + (ch >> 4);
        if (row < N) featv[(size_t)row * 16 + (ch & 15)] = As2v[ch];
    }
}

// Layer-2 residual + Layer-3 projections, fused; h3 never stored.
// feat3 written with stride 8 (padded) for aligned float4 gathers in pull6f.
__global__ __launch_bounds__(256) void mfma_res_k(const _Float16* __restrict__ A,
                                                  const float4* __restrict__ Wf,
                                                  const _Float16* __restrict__ rsth,
                                                  const float* __restrict__ b2,
                                                  const float* __restrict__ W3,
                                                  const float* __restrict__ resW3,
                                                  const float* __restrict__ b3,
                                                  float* __restrict__ feat3,
                                                  float* __restrict__ res3, int N) {
    __shared__ float4 WsF[2048];
    __shared__ float4 AsF[1024];
    MFMA_STAGE_AND_LOOP()

    float4* As2v = (float4*)AsF + (w << 8);
#pragma unroll
    for (int ii = 0; ii < 4; ii++) {
        int ch = ii * 64 + lane;
        int row = row0 + (w << 4) + (ch >> 4);
        float4 v = make_float4(0.f, 0.f, 0.f, 0.f);
        if (row < N) v = ((const float4*)rsth)[(size_t)row * 16 + (ch & 15)];
        As2v[ch] = v;
    }
    __asm__ volatile("s_waitcnt lgkmcnt(0)" ::: "memory");
    const _Float16* As2 = (const _Float16*)As2v;

    float b2v[8];
#pragma unroll
    for (int t = 0; t < 8; t++) b2v[t] = b2[(t << 4) + c16];

    float hv[8][4];
#pragma unroll
    for (int t = 0; t < 8; t++)
#pragma unroll
        for (int j = 0; j < 4; j++) {
            float rv = (float)As2[((rg << 2) + j) * 128 + (t << 4) + c16];
            hv[t][j] = fmaxf(acc[t][j] + rv + b2v[t], 0.f);
        }

    float f3[4][6], r3[4][6];
#pragma unroll
    for (int j = 0; j < 4; j++)
#pragma unroll
        for (int h = 0; h < 6; h++) {
            f3[j][h] = 0.f;
            r3[j][h] = 0.f;
        }
#pragma unroll
    for (int t = 0; t < 8; t++) {
        int col = (t << 4) + c16;
        const float* w3p = W3 + col * 6;
        const float* rwp = resW3 + col * 6;
#pragma unroll
        for (int h = 0; h < 6; h++) {
            float w3 = w3p[h], rw = rwp[h];
#pragma unroll
            for (int j = 0; j < 4; j++) {
                f3[j][h] = fmaf(hv[t][j], w3, f3[j][h]);
                r3[j][h] = fmaf(hv[t][j], rw, r3[j][h]);
            }
        }
    }
#pragma unroll
    for (int m = 1; m < 16; m <<= 1)
#pragma unroll
        for (int j = 0; j < 4; j++)
#pragma unroll
            for (int h = 0; h < 6; h++) {
                f3[j][h] += __shfl_xor(f3[j][h], m);
                r3[j][h] += __shfl_xor(r3[j][h], m);
            }
    if (c16 == 0) {
#pragma unroll
        for (int j = 0; j < 4; j++) {
            int row = row0 + (w << 4) + (rg << 2) + j;
            if (row < N) {
#pragma unroll
                for (int h = 0; h < 6; h++) {
                    feat3[(size_t)row * 8 + h] = f3[j][h];
                    res3[row * 6 + h] = r3[j][h] + b3[h];
                }
            }
        }
    }
}

// ---- Pull aggregation (H=4, D=32, fp16 in/out): one wave per node ----
// (R8 version — measured best. Wave-uniform beg/end -> readfirstlane ->
// scalar CSR walk; convergent per-node edge loop; half2 per lane.)
template <bool BR>
__global__ __launch_bounds__(256) void pull2_k(const int* __restrict__ row_beg,
                                               const int* __restrict__ row_end,
                                               const int* __restrict__ csr_src,
                                               const float* __restrict__ el,
                                               const float* __restrict__ er,
                                               const __half* __restrict__ feat_h,
                                               const float* __restrict__ bias,
                                               __half* __restrict__ outp, int N) {
    int n = (blockIdx.x << 2) + (threadIdx.x >> 6);
    if (n >= N) return;
    unsigned l = threadIdx.x & 63;
    unsigned h = l >> 4;
    float erd = er[((unsigned)n << 2) + h];
    const __half2* feat2 = (const __half2*)feat_h;
    int beg = __builtin_amdgcn_readfirstlane(row_beg[n]);
    int end = __builtin_amdgcn_readfirstlane(row_end[n]);
    float ax = 0.f, ay = 0.f, den = 0.f;
    int p = beg;
    for (; p + 4 <= end; p += 4) {
        int s0 = csr_src[p], s1 = csr_src[p + 1];
        int s2 = csr_src[p + 2], s3 = csr_src[p + 3];
        float e0 = el[((unsigned)s0 << 2) + h];
        float e1 = el[((unsigned)s1 << 2) + h];
        float e2 = el[((unsigned)s2 << 2) + h];
        float e3 = el[((unsigned)s3 << 2) + h];
        __half2 g0 = feat2[((unsigned)s0 << 6) + l];
        __half2 g1 = feat2[((unsigned)s1 << 6) + l];
        __half2 g2 = feat2[((unsigned)s2 << 6) + l];
        __half2 g3 = feat2[((unsigned)s3 << 6) + l];
        float x0 = e0 + erd, x1 = e1 + erd, x2 = e2 + erd, x3 = e3 + erd;
        x0 = fmaxf(x0, NEG * x0);
        x1 = fmaxf(x1, NEG * x1);
        x2 = fmaxf(x2, NEG * x2);
        x3 = fmaxf(x3, NEG * x3);
        float w0 = __expf(x0), w1 = __expf(x1), w2 = __expf(x2), w3 = __expf(x3);
        float2 f0 = __half22float2(g0), f1 = __half22float2(g1);
        float2 f2 = __half22float2(g2), f3 = __half22float2(g3);
        den += (w0 + w1) + (w2 + w3);
        ax = fmaf(w0, f0.x, ax);
        ay = fmaf(w0, f0.y, ay);
        ax = fmaf(w1, f1.x, ax);
        ay = fmaf(w1, f1.y, ay);
        ax = fmaf(w2, f2.x, ax);
        ay = fmaf(w2, f2.y, ay);
        ax = fmaf(w3, f3.x, ax);
        ay = fmaf(w3, f3.y, ay);
    }
    for (; p < end; p++) {
        int s0 = csr_src[p];
        float e0 = el[((unsigned)s0 << 2) + h];
        __half2 g0 = feat2[((unsigned)s0 << 6) + l];
        float x0 = e0 + erd;
        x0 = fmaxf(x0, NEG * x0);
        float w0 = __expf(x0);
        float2 f0 = __half22float2(g0);
        den += w0;
        ax = fmaf(w0, f0.x, ax);
        ay = fmaf(w0, f0.y, ay);
    }
    float inv = 1.f / den;  // den >= 1 edge (self-loops)
    float vx = ax * inv, vy = ay * inv;
    if (BR) {
        float2 b = ((const float2*)bias)[l];
        vx = fmaxf(vx + b.x, 0.f);
        vy = fmaxf(vy + b.y, 0.f);
    }
    ((__half2*)outp)[((size_t)n << 6) + l] = __floats2half2_rn(vx, vy);
}

// Layer 3 pull + residual + head-mean, one thread per node (D=1, H=6).
// feat3 stride 8 -> two aligned float4 loads per edge.
__global__ __launch_bounds__(256) void pull6f_k(const int* __restrict__ row_beg,
                                                const int* __restrict__ row_end,
                                                const int* __restrict__ csr_src,
                                                const float* __restrict__ feat3,
                                                const float* __restrict__ al3,
                                                const float* __restrict__ ar3,
                                                const float* __restrict__ res3,
                                                float* __restrict__ out, int N) {
    int n = blockIdx.x * blockDim.x + threadIdx.x;
    if (n >= N) return;
    const float4* f4p = (const float4*)feat3;  // stride 2 per node
    float a3[6], fdr[6], acc[6], den[6];
#pragma unroll
    for (int h = 0; h < 6; h++) {
        a3[h] = al3[h];
        fdr[h] = feat3[(size_t)n * 8 + h] * ar3[h];
        acc[h] = 0.f;
        den[h] = 0.f;
    }
    int beg = row_beg[n], end = row_end[n];
    for (int p = beg; p < end; p++) {
        int s = csr_src[p];
        float4 fa = f4p[(size_t)s * 2];
        float4 fb = f4p[(size_t)s * 2 + 1];
        float f[6] = {fa.x, fa.y, fa.z, fa.w, fb.x, fb.y};
#pragma unroll
        for (int h = 0; h < 6; h++) {
            float x = fmaf(f[h], a3[h], fdr[h]);
            x = fmaxf(x, NEG * x);
            float w = __expf(x);
            den[h] += w;
            acc[h] = fmaf(w, f[h], acc[h]);
        }
    }
    float m = 0.f;
#pragma unroll
    for (int h = 0; h < 6; h++) m += acc[h] / den[h] + res3[n * 6 + h];
    out[n] = m * (1.f / 6.f);
}

extern "C" void kernel_launch(void* const* d_in, const int* in_sizes, int n_in,
                              void* d_out, int out_size, void* d_ws, size_t ws_size,
                              hipStream_t stream) {
    const float* x = (const float*)d_in[0];
    const int* src = (const int*)d_in[1];
    const int* dst = (const int*)d_in[2];
    const float* W1 = (const float*)d_in[3];
    const float* al1 = (const float*)d_in[4];
    const float* ar1 = (const float*)d_in[5];
    const float* b1 = (const float*)d_in[6];
    const float* W2 = (const float*)d_in[7];
    const float* al2 = (const float*)d_in[8];
    const float* ar2 = (const float*)d_in[9];
    const float* b2 = (const float*)d_in[10];
    const float* resW2 = (const float*)d_in[11];
    const float* W3 = (const float*)d_in[12];
    const float* al3 = (const float*)d_in[13];
    const float* ar3 = (const float*)d_in[14];
    const float* b3 = (const float*)d_in[15];
    const float* resW3 = (const float*)d_in[16];
    float* out = (float*)d_out;

    const int N = in_sizes[0] / 64;
    const int E = in_sizes[1];
    const int NB = (N + 127) >> BUCKET_SHIFT;

    // ---- workspace layout (float units) ----
    float* ws = (float*)d_ws;
    __half* featA = (__half*)ws;                     // N*128 fp16
    __half* h2h = (__half*)(ws + (size_t)N * 64);    // N*128 fp16 (layer-1 out)
    __half* rsth = (__half*)(ws + (size_t)N * 128);  // N*128 fp16 (layer-2 agg out)
    float* el = ws + (size_t)N * 192;                // N*4
    float* er = el + (size_t)N * 4;                  // N*4
    float* feat3 = el;                               // N*8 (stride 8) aliases el+er
    float* res3 = ws + (size_t)N * 200;              // N*6
    float* W2f = res3 + (size_t)N * 6;               // 8192 (2048 float4)
    float* rW2f = W2f + 8192;                        // 8192
    int* ip = (int*)(rW2f + 8192);
    int* cursor = ip;                                // 512 (memset)
    int* row_beg = cursor + 512;                     // N
    int* row_end = row_beg + N;                      // N
    unsigned* part = (unsigned*)(row_end + N);       // NB*CAP
    int* csr_src = (int*)(part + (size_t)NB * CAP);  // NB*CAP

    const int gN = (N + 255) / 256;
    const int gN64 = (N + 63) / 64;
    const int gNw = (N + 3) / 4;  // wave-per-node pull blocks
    const int gP = (E + PCHUNK - 1) / PCHUNK;

    hipMemsetAsync(cursor, 0, sizeof(int) * 512, stream);
    // Stage 1 (fused, independent): weight fragments + edge partition.
    stage1_k<<<16 + gP, 256, 0, stream>>>(W2, resW2, (float4*)W2f, (float4*)rW2f,
                                          src, dst, cursor, part, E, NB);
    // Stage 2 (fused, independent): bucket CSR + layer-1 GEMM.
    stage2_k<<<NB + gN64, 256, 0, stream>>>(cursor, part, csr_src, row_beg, row_end,
                                            NB, x, W1, al1, ar1, featA, el, er, N);

    // ---- Layer 1 pull ----
    pull2_k<true><<<gNw, 256, 0, stream>>>(row_beg, row_end, csr_src, el, er,
                                           featA, b1, h2h, N);

    // ---- Layer 2: MFMA GEMM + pull + fused residual/layer-3 projections ----
    mfma_el_k<<<gN64, 256, 0, stream>>>((const _Float16*)h2h, (const float4*)W2f,
                                        al2, ar2, (_Float16*)featA, el, er, N);
    pull2_k<false><<<gNw, 256, 0, stream>>>(row_beg, row_end, csr_src, el, er,
                                            featA, nullptr, rsth, N);
    mfma_res_k<<<gN64, 256, 0, stream>>>((const _Float16*)h2h, (const float4*)rW2f,
                                         (const _Float16*)rsth, b2, W3, resW3, b3,
                                         feat3, res3, N);

    // ---- Layer 3: pull + residual + mean (fused) ----
    pull6f_k<<<gN, 256, 0, stream>>>(row_beg, row_end, csr_src, feat3, al3, ar3,
                                     res3, out, N);
}